// Round 13
// baseline (462.341 us; speedup 1.0000x reference)
//
#include <hip/hip_runtime.h>

#define NN    100000
#define NE    1600000
#define DIM   64
#define NREL  8
#define NSEG  (NN * NREL)                       // 800000 (dst,rel) segments
#define NTOT  (NSEG + 1)                        // off[] has a sentinel end
#define CHUNK 1024
#define NBLK  ((NTOT + CHUNK - 1) / CHUNK)      // 782
#define KTOT  (9 * DIM)                         // 576: 8 relations + root (B stack)
#define KAGG  (8 * DIM)                         // 512: A-tile has no root slot
#define APAD  (KTOT + 8)                        // MID-path LDS row pad
#define APAD2 (KAGG + 8)                        // 520 bf16 per A-tile row
#define ESPMAX (NE + NSEG)                      // padded edge list worst case
#define SEGB  2048                              // segments per bucket
#define NBUCK ((NSEG + SEGB - 1) / SEGB)        // 391 buckets

typedef unsigned short bf16u;
using short8  = __attribute__((ext_vector_type(8))) short;
using bfx4    = __attribute__((ext_vector_type(4))) unsigned short;
using f32x4   = __attribute__((ext_vector_type(4))) float;
using float4v = __attribute__((ext_vector_type(4))) float;

#if defined(__has_builtin)
#if __has_builtin(__builtin_amdgcn_make_buffer_rsrc) && \
    __has_builtin(__builtin_amdgcn_raw_buffer_load_b32) && \
    __has_builtin(__builtin_amdgcn_raw_buffer_store_b32)
#define HAVE_BUF 1
#endif
#endif

#ifdef HAVE_BUF
__device__ __forceinline__ __amdgpu_buffer_rsrc_t mk_rsrc(const void* p, unsigned bytes) {
    return __builtin_amdgcn_make_buffer_rsrc(const_cast<void*>(p), (short)0,
                                             (int)bytes, 0x00020000);
}
#endif

__device__ __forceinline__ bf16u f2bf(float v) {   // f32 -> bf16 RNE
    unsigned b = __float_as_uint(v);
    return (bf16u)((b + 0x7FFFu + ((b >> 16) & 1u)) >> 16);
}
__device__ __forceinline__ float bf2f(bf16u u) {
    return __uint_as_float((unsigned)u << 16);
}

// exclusive prefix over blockDim.x values
__device__ __forceinline__ int block_exscan(int v, int* lds) {
    int tid = threadIdx.x;
    lds[tid] = v;
    __syncthreads();
    for (int s = 1; s < (int)blockDim.x; s <<= 1) {
        int t = (tid >= s) ? lds[tid - s] : 0;
        __syncthreads();
        lds[tid] += t;
        __syncthreads();
    }
    return lds[tid] - v;
}

// ---------------- bucketed CSR build (BIG path) ----------------
__global__ __launch_bounds__(256) void bcount_k(const int* __restrict__ dst,
                                                const int* __restrict__ et,
                                                int* __restrict__ bcnt) {
    __shared__ int bl[NBUCK];
    for (int i = threadIdx.x; i < NBUCK; i += 256) bl[i] = 0;
    __syncthreads();
    const int base = blockIdx.x * 4096;
#pragma unroll
    for (int j = 0; j < 16; ++j) {
        int i = base + j * 256 + threadIdx.x;
        if (i < NE) atomicAdd(&bl[(dst[i] * NREL + et[i]) >> 11], 1);
    }
    __syncthreads();
    for (int i = threadIdx.x; i < NBUCK; i += 256)
        if (bl[i]) atomicAdd(&bcnt[i], bl[i]);
}

__global__ __launch_bounds__(512) void bscan_k(const int* __restrict__ bcnt,
                                               int* __restrict__ bstart,
                                               int* __restrict__ bcur) {
    __shared__ int lds[512];
    int v = (threadIdx.x < NBUCK) ? bcnt[threadIdx.x] : 0;
    int e = block_exscan(v, lds);
    if (threadIdx.x < NBUCK) { bstart[threadIdx.x] = e; bcur[threadIdx.x] = e; }
    if (threadIdx.x == NBUCK - 1) bstart[NBUCK] = e + v;
}

// block-local binning append: packed (src<<11 | c&2047) into per-bucket dense regions
__global__ __launch_bounds__(256) void part1_k(const int* __restrict__ src,
                                               const int* __restrict__ dst,
                                               const int* __restrict__ et,
                                               int* __restrict__ bcur,
                                               unsigned* __restrict__ tmp) {
    __shared__ int cntl[NBUCK];
    __shared__ int basel[NBUCK];
    for (int i = threadIdx.x; i < NBUCK; i += 256) cntl[i] = 0;
    __syncthreads();
    const int base = blockIdx.x * 2048;
    int cs[8], rs[8]; unsigned pw[8];
#pragma unroll
    for (int j = 0; j < 8; ++j) {
        int i = base + j * 256 + threadIdx.x;
        cs[j] = -1;
        if (i < NE) {
            cs[j] = dst[i] * NREL + et[i];
            pw[j] = ((unsigned)src[i] << 11) | ((unsigned)cs[j] & 2047u);
            rs[j] = atomicAdd(&cntl[cs[j] >> 11], 1);
        }
    }
    __syncthreads();
    for (int i = threadIdx.x; i < NBUCK; i += 256)
        basel[i] = cntl[i] ? atomicAdd(&bcur[i], cntl[i]) : 0;
    __syncthreads();
#pragma unroll
    for (int j = 0; j < 8; ++j)
        if (cs[j] >= 0)
            tmp[basel[cs[j] >> 11] + rs[j]] = pw[j];
}

// per-bucket dense segment counts (from packed tmp)
__global__ __launch_bounds__(256) void ncount_k(const unsigned* __restrict__ tmp,
                                                const int* __restrict__ bstart,
                                                int* __restrict__ cnt) {
    __shared__ int rk[SEGB];
    const int b = blockIdx.x, c0 = b * SEGB;
    const int nsb = min(SEGB, NSEG - c0);
    for (int i = threadIdx.x; i < SEGB; i += 256) rk[i] = 0;
    __syncthreads();
    const int e0 = bstart[b], e1 = bstart[b + 1];
    for (int e = e0 + threadIdx.x; e < e1; e += 256)
        atomicAdd(&rk[tmp[e] & 2047u], 1);
    __syncthreads();
    for (int i = threadIdx.x; i < nsb; i += 256) cnt[c0 + i] = rk[i];
}

// per-bucket scatter into L2-resident esp window
__global__ __launch_bounds__(256) void part2_k(const unsigned* __restrict__ tmp,
                                               const int* __restrict__ bstart,
                                               const int* __restrict__ offp,
                                               int* __restrict__ esp) {
    __shared__ int rk[SEGB];
    const int b = blockIdx.x, c0 = b * SEGB;
    for (int i = threadIdx.x; i < SEGB; i += 256) rk[i] = 0;
    __syncthreads();
    const int e0 = bstart[b], e1 = bstart[b + 1];
    for (int e = e0 + threadIdx.x; e < e1; e += 256) {
        unsigned w = tmp[e];
        int lc = (int)(w & 2047u);
        int r = atomicAdd(&rk[lc], 1);
        esp[offp[c0 + lc] + r] = (int)(w >> 11);
    }
}

// ---------------- legacy CSR build (MID/SMALL fallbacks) ----------------
__global__ __launch_bounds__(256) void count_k(const int* __restrict__ dst,
                                               const int* __restrict__ et,
                                               int* __restrict__ cnt, int E) {
    int i = blockIdx.x * 256 + threadIdx.x;
    if (i < E) atomicAdd(&cnt[dst[i] * NREL + et[i]], 1);
}

__global__ __launch_bounds__(256) void scanA_p(const int* __restrict__ cnt,
                                               int* __restrict__ bsum) {
    __shared__ int lds[256];
    int base = blockIdx.x * CHUNK + threadIdx.x * 4;
    int s = 0;
#pragma unroll
    for (int j = 0; j < 4; ++j) {
        int i = base + j;
        if (i < NSEG) { int v = cnt[i]; s += v + (v & 1); }
    }
    int e = block_exscan(s, lds);
    if (threadIdx.x == 255) bsum[blockIdx.x] = e + s;
}

__global__ __launch_bounds__(1024) void scanB(int* __restrict__ bsum) {
    __shared__ int lds[1024];
    int v = (threadIdx.x < NBLK) ? bsum[threadIdx.x] : 0;
    int e = block_exscan(v, lds);
    if (threadIdx.x < NBLK) bsum[threadIdx.x] = e;
}

__global__ __launch_bounds__(256) void scanC_p(const int* __restrict__ cnt,
                                               const int* __restrict__ bsum,
                                               int* __restrict__ offp,
                                               float* __restrict__ inv,
                                               int* __restrict__ esp) {
    __shared__ int lds[256];
    int base = blockIdx.x * CHUNK + threadIdx.x * 4;
    int c4[4], v4[4]; int s = 0;
#pragma unroll
    for (int j = 0; j < 4; ++j) {
        int i = base + j;
        c4[j] = (i < NSEG) ? cnt[i] : 0;
        v4[j] = c4[j] + (c4[j] & 1);
        s += v4[j];
    }
    int e = block_exscan(s, lds) + bsum[blockIdx.x];
#pragma unroll
    for (int j = 0; j < 4; ++j) {
        int i = base + j;
        if (i < NSEG) {
            offp[i] = e;
            inv[i]  = (c4[j] > 0) ? 1.0f / (float)c4[j] : 0.0f;
            if (c4[j] & 1) esp[e + c4[j]] = NN;       // dummy -> zero row
            e += v4[j];
        } else if (i == NSEG) { offp[i] = e; }
    }
}

__global__ __launch_bounds__(256) void scanA(const int* __restrict__ cnt,
                                             int* __restrict__ bsum) {
    __shared__ int lds[256];
    int base = blockIdx.x * CHUNK + threadIdx.x * 4;
    int s = 0;
#pragma unroll
    for (int j = 0; j < 4; ++j) { int i = base + j; if (i < NSEG) s += cnt[i]; }
    int e = block_exscan(s, lds);
    if (threadIdx.x == 255) bsum[blockIdx.x] = e + s;
}

__global__ __launch_bounds__(256) void scanC(const int* __restrict__ cnt,
                                             const int* __restrict__ bsum,
                                             int* __restrict__ off,
                                             int* __restrict__ cur) {
    __shared__ int lds[256];
    int base = blockIdx.x * CHUNK + threadIdx.x * 4;
    int v[4]; int s = 0;
#pragma unroll
    for (int j = 0; j < 4; ++j) { int i = base + j; v[j] = (i < NSEG) ? cnt[i] : 0; s += v[j]; }
    int e = block_exscan(s, lds) + bsum[blockIdx.x];
#pragma unroll
    for (int j = 0; j < 4; ++j) {
        int i = base + j;
        if (i < NSEG)       { off[i] = e; cur[i] = e; e += v[j]; }
        else if (i == NSEG) { off[i] = e; }
    }
}

__global__ __launch_bounds__(256) void scatter_k(const int* __restrict__ src,
                                                 const int* __restrict__ dst,
                                                 const int* __restrict__ et,
                                                 int* __restrict__ cur,
                                                 int* __restrict__ es, int E) {
    int i = blockIdx.x * 256 + threadIdx.x;
    if (i < E) {
        int c = dst[i] * NREL + et[i];
        int p = atomicAdd(&cur[c], 1);
        es[p] = src[i];
    }
}

// ---------------- f32 -> bf16 convert (x -> xb0) + zero rows of xb0 AND xb1 ----------------
__global__ __launch_bounds__(256) void xcvt_k(const float* __restrict__ x,
                                              bf16u* __restrict__ xb,
                                              bf16u* __restrict__ xb1) {
    int i = blockIdx.x * 256 + threadIdx.x;          // 4 elems per thread
    int e4 = i * 4;
    if (e4 < NN * DIM) {
        float4v v = *(const float4v*)(x + e4);
        bfx4 o;
        o.x = f2bf(v.x); o.y = f2bf(v.y); o.z = f2bf(v.z); o.w = f2bf(v.w);
        *(bfx4*)(xb + e4) = o;
    } else if (e4 < (NN + 1) * DIM) {
        bfx4 z = {0, 0, 0, 0};
        *(bfx4*)(xb + e4)  = z;                      // zero row for dummy edges
        *(bfx4*)(xb1 + e4) = z;                      // layer-1 intermediate zero row
    }
}

// ---------------- B-stack transpose: Bt[l][n][k] = Bs[l][k][n] in bf16 ----------------
__global__ __launch_bounds__(256) void btk(const float* __restrict__ W,
                                           const float* __restrict__ R,
                                           bf16u* __restrict__ BtG) {
    int idx = blockIdx.x * 256 + threadIdx.x;     // [2][64][576]
    if (idx >= 2 * DIM * KTOT) return;
    int k = idx % KTOT;
    int n = (idx / KTOT) & (DIM - 1);
    int l = idx / (KTOT * DIM);
    float v;
    if (k < 8 * DIM) v = W[(((size_t)l * NREL + (k >> 6)) * DIM + (k & 63)) * DIM + n];
    else             v = R[((size_t)l * DIM + (k - 8 * DIM)) * DIM + n];
    BtG[idx] = f2bf(v);
}

// ---------------- BIG path: FUSED aggregate(LDS) + MFMA GEMM ----------------
// 512 thr / 8 waves / 64 dsts per block. Phase 1: each wave pair-gathers its
// 8 dsts (16-deep pipeline) into the LDS A-tile. Phase 2: C = [A|xroot]@Bstack.
// No global Ag round-trip (saves ~400 MB HBM).
template<bool BF16OUT>
__global__ __launch_bounds__(512, 4) void fused_k(
    const bf16u* __restrict__ xb, const int* __restrict__ offp,
    const float* __restrict__ invf, const int* __restrict__ esp,
    const bf16u* __restrict__ BtG, const float* __restrict__ bias,
    void* __restrict__ outv)
{
    __shared__ bf16u A[64 * APAD2];                  // 66,560 B -> 2 blocks/CU
    const int tid  = threadIdx.x;
    const int lane = tid & 63;
    const int wv   = tid >> 6;
    const int base = blockIdx.x * 64;
    const int d0   = base + wv * 8;                  // NN%8==0: wave all-valid or all-invalid

    if (d0 < NN) {
        const int c0 = d0 * NREL;
#ifdef HAVE_BUF
        const __amdgpu_buffer_rsrc_t xrsrc = mk_rsrc(xb,  (unsigned)((NN + 1) * DIM * 2));
        const __amdgpu_buffer_rsrc_t ersrc = mk_rsrc(esp, (unsigned)(ESPMAX * 4));
        const int xoff4 = (lane & 31) * 4;
#define ESLD(pos)  (int)__builtin_amdgcn_raw_buffer_load_b32(ersrc, (pos) * 4, 0, 0)
#define XLD(sv)    __builtin_amdgcn_raw_buffer_load_b32(xrsrc, ((sv) << 7) + xoff4, 0, 0)
#else
#define ESLD(pos)  esp[min((pos), ESPMAX - 1)]
#define XLD(sv)    (*(const unsigned*)(xb + (size_t)(sv) * DIM + (lane & 31) * 2))
#endif
        int offv = offp[c0 + 1 + lane];              // bounds 1..64 (seg ends)
        int invv = ((const int*)invf)[c0 + lane];    // 1/real_cnt per segment
        int pBase = __builtin_amdgcn_readfirstlane(offp[c0]); // even
        int pEnd  = __builtin_amdgcn_readlane(offv, 63);

        int idsbase = pBase;
        int ids = ESLD(idsbase + lane);

        unsigned q0 = 0, q1 = 0, q2 = 0, q3 = 0, q4 = 0, q5 = 0, q6 = 0, q7 = 0,
                 q8 = 0, q9 = 0, qa = 0, qb = 0, qc = 0, qd = 0, qe = 0, qf = 0;
        {   // prime 16 pair-slots (idx <= 31, no reload needed)
            int pf = pBase;
#define PRIME(Q) if (pf < pEnd) {                                             \
            int idx = pf - idsbase;                                           \
            int sv0 = __builtin_amdgcn_readlane(ids, idx);                    \
            int sv1 = __builtin_amdgcn_readlane(ids, idx + 1);                \
            int sv  = (lane < 32) ? sv0 : sv1;                                \
            Q = XLD(sv); }                                                    \
            pf += 2;
            PRIME(q0) PRIME(q1) PRIME(q2) PRIME(q3)
            PRIME(q4) PRIME(q5) PRIME(q6) PRIME(q7)
            PRIME(q8) PRIME(q9) PRIME(qa) PRIME(qb)
            PRIME(qc) PRIME(qd) PRIME(qe) PRIME(qf)
#undef PRIME
        }
        int seg = 0, p = pBase;
        int se      = __builtin_amdgcn_readlane(offv, 0);
        float invn  = __int_as_float(__builtin_amdgcn_readlane(invv, 0));
        float accA = 0.f, accB = 0.f;

#define STEP(Q) {                                                             \
        while (p == se) {   /* flush segment (handles empty segs) */          \
            float ta = accA + __shfl_xor(accA, 32);                           \
            float tb = accB + __shfl_xor(accB, 32);                           \
            unsigned pk = (unsigned)f2bf(ta * invn)                           \
                        | ((unsigned)f2bf(tb * invn) << 16);                  \
            if (lane < 32)                                                    \
                *(unsigned*)(A + (wv * 8 + (seg >> 3)) * APAD2                \
                               + (seg & 7) * DIM + lane * 2) = pk;            \
            accA = 0.f; accB = 0.f;                                           \
            if (++seg >= 64) goto agg_done;                                   \
            se   = __builtin_amdgcn_readlane(offv, seg);                      \
            invn = __int_as_float(__builtin_amdgcn_readlane(invv, seg));      \
        }                                                                     \
        accA += __uint_as_float(Q << 16);                                     \
        accB += __uint_as_float(Q & 0xffff0000u);                             \
        int pn = p + 32;                                                      \
        if (pn < pEnd) {                                                      \
            int idx = pn - idsbase;                                           \
            if (idx >= 64) { idsbase = pn;                                    \
                ids = ESLD(idsbase + lane); idx = 0; }                        \
            int sv0 = __builtin_amdgcn_readlane(ids, idx);                    \
            int sv1 = __builtin_amdgcn_readlane(ids, idx + 1);                \
            int sv  = (lane < 32) ? sv0 : sv1;                                \
            Q = XLD(sv);                                                      \
        }                                                                     \
        p += 2; }

        for (;;) { STEP(q0) STEP(q1) STEP(q2) STEP(q3)
                   STEP(q4) STEP(q5) STEP(q6) STEP(q7)
                   STEP(q8) STEP(q9) STEP(qa) STEP(qb)
                   STEP(qc) STEP(qd) STEP(qe) STEP(qf) }
agg_done: ;
#undef STEP
#undef ESLD
#undef XLD
    } else {
        // invalid wave: zero its 8 A-tile rows (512 bf16 each)
#pragma unroll
        for (int i = 0; i < 8; ++i) {
            unsigned* row = (unsigned*)(A + (wv * 8 + i) * APAD2);
#pragma unroll
            for (int j = 0; j < 4; ++j) row[j * 64 + lane] = 0;
        }
    }
    __syncthreads();

    // ---- phase 2: C[64x64] = [A(512, LDS) | xroot(64, global)] @ Bstack ----
    const int l15 = lane & 15, hw = lane >> 4;
    const int tid0 = wv * 2;                 // two N-adjacent 16x16 tiles per wave
    const int tm = tid0 >> 2, tn0 = tid0 & 3;
    const bf16u* Arow = &A[(tm * 16 + l15) * APAD2 + hw * 8];
    const bf16u* xrow = xb + (size_t)min(base + tm * 16 + l15, NN - 1) * DIM + hw * 8;
    const bf16u* B0   = &BtG[(size_t)(tn0 * 16 + l15) * KTOT + hw * 8];
    const bf16u* B1   = B0 + 16 * KTOT;
    f32x4 acc0 = {0.f, 0.f, 0.f, 0.f}, acc1 = {0.f, 0.f, 0.f, 0.f};
#pragma unroll
    for (int ks = 0; ks < KTOT / 32; ++ks) {         // 16 LDS steps + 2 root steps
        short8 af = (ks < 16) ? *(const short8*)(Arow + ks * 32)
                              : *(const short8*)(xrow + (ks - 16) * 32);
        short8 b0 = *(const short8*)(B0 + ks * 32);
        short8 b1 = *(const short8*)(B1 + ks * 32);
        acc0 = __builtin_amdgcn_mfma_f32_16x16x32_bf16(af, b0, acc0, 0, 0, 0);
        acc1 = __builtin_amdgcn_mfma_f32_16x16x32_bf16(af, b1, acc1, 0, 0, 0);
    }
    // C/D: col = lane&15, row = (lane>>4)*4 + reg   [m89-verified]
    int col0 = tn0 * 16 + l15;
    int r0   = tm * 16 + hw * 4;
    float bv0 = bias[col0], bv1 = bias[col0 + 16];
#pragma unroll
    for (int j = 0; j < 4; ++j) {
        int row = base + r0 + j;
        if (row < NN) {
            if constexpr (BF16OUT) {
                bf16u* out = (bf16u*)outv;
                out[(size_t)row * DIM + col0]      = f2bf(acc0[j] + bv0);
                out[(size_t)row * DIM + col0 + 16] = f2bf(acc1[j] + bv1);
            } else {
                float* out = (float*)outv;
                out[(size_t)row * DIM + col0]      = acc0[j] + bv0;
                out[(size_t)row * DIM + col0 + 16] = acc1[j] + bv1;
            }
        }
    }
}

// ---------------- MID path: round-4 fused kernel (f32 gather, unpadded CSR) ----------------
__global__ __launch_bounds__(512, 4) void layer_k(
    const float* __restrict__ xin, const bf16u* __restrict__ BtG,
    const float* __restrict__ bias, const int* __restrict__ off,
    const int* __restrict__ es, float* __restrict__ out)
{
    __shared__ bf16u A[64 * APAD];
    const int lane = threadIdx.x & 63;
    const int wv   = threadIdx.x >> 6;
    const int base = blockIdx.x * 64;
    const int d0   = base + wv * 8;
    const int nds  = min(8, NN - d0);
    bf16u* Aw = &A[wv * 8 * APAD];

    if (nds > 0) {
        const int c0   = d0 * NREL;
        const int nseg = nds * NREL;
        int s1v = off[min(c0 + lane + 1, NSEG)];
        int pBase = off[min(c0, NSEG)];
        pBase = __builtin_amdgcn_readfirstlane(pBase);
        int pEnd  = __builtin_amdgcn_readlane(s1v, nseg - 1);

        float xroot[8];
#pragma unroll
        for (int i = 0; i < 8; ++i)
            xroot[i] = xin[(size_t)min(d0 + i, NN - 1) * DIM + lane];

        int idsbase = pBase;
        int ids = es[min(idsbase + lane, NE - 1)];

        float q0 = 0.f, q1 = 0.f, q2 = 0.f, q3 = 0.f,
              q4 = 0.f, q5 = 0.f, q6 = 0.f, q7 = 0.f;
        {
            int pf = pBase;
#define PRIME(Q) if (pf < pEnd) { int idx = pf - idsbase;                     \
        int sv = __builtin_amdgcn_readlane(ids, idx);                         \
        Q = xin[(size_t)sv * DIM + lane]; } ++pf;
            PRIME(q0) PRIME(q1) PRIME(q2) PRIME(q3)
            PRIME(q4) PRIME(q5) PRIME(q6) PRIME(q7)
#undef PRIME
        }
        int seg = 0, segStart = pBase, p = pBase;
        int se = __builtin_amdgcn_readlane(s1v, 0);
        float acc = 0.f;

#define STEP(Q) {                                                             \
        while (p == se) {                                                     \
            int n = se - segStart;                                            \
            float invn = (n > 0) ? 1.0f / (float)n : 0.f;                     \
            Aw[(seg >> 3) * APAD + (seg & 7) * DIM + lane] = f2bf(acc * invn);\
            acc = 0.f; segStart = p;                                          \
            if (++seg >= nseg) goto agg_done;                                 \
            se = __builtin_amdgcn_readlane(s1v, seg);                         \
        }                                                                     \
        acc += Q;                                                             \
        int pn = p + 8;                                                       \
        if (pn < pEnd) {                                                      \
            int idx = pn - idsbase;                                           \
            if (idx >= 64) { idsbase = pn;                                    \
                ids = es[min(idsbase + lane, NE - 1)]; idx = 0; }             \
            int sv = __builtin_amdgcn_readlane(ids, idx);                     \
            Q = xin[(size_t)sv * DIM + lane];                                 \
        }                                                                     \
        ++p; }

        for (;;) { STEP(q0) STEP(q1) STEP(q2) STEP(q3)
                   STEP(q4) STEP(q5) STEP(q6) STEP(q7) }
agg_done: ;
#undef STEP

#pragma unroll
        for (int i = 0; i < 8; ++i) {
            if (i < nds) Aw[i * APAD + 8 * DIM + lane] = f2bf(xroot[i]);
            else {
#pragma unroll
                for (int r = 0; r < 9; ++r) Aw[i * APAD + r * DIM + lane] = 0;
            }
        }
    } else {
#pragma unroll
        for (int i = 0; i < 8; ++i)
#pragma unroll
            for (int r = 0; r < 9; ++r) Aw[i * APAD + r * DIM + lane] = 0;
    }
    __syncthreads();

    const int l15 = lane & 15, hw = lane >> 4;
    const int tid0 = wv * 2;
    const int tm = tid0 >> 2, tn0 = tid0 & 3;
    const bf16u* Arow = &A[(tm * 16 + l15) * APAD + hw * 8];
    const bf16u* B0   = &BtG[(size_t)(tn0 * 16 + l15) * KTOT + hw * 8];
    const bf16u* B1   = B0 + 16 * KTOT;
    f32x4 acc0 = {0.f, 0.f, 0.f, 0.f}, acc1 = {0.f, 0.f, 0.f, 0.f};
#pragma unroll
    for (int ks = 0; ks < KTOT / 32; ++ks) {
        short8 af = *(const short8*)(Arow + ks * 32);
        short8 b0 = *(const short8*)(B0 + ks * 32);
        short8 b1 = *(const short8*)(B1 + ks * 32);
        acc0 = __builtin_amdgcn_mfma_f32_16x16x32_bf16(af, b0, acc0, 0, 0, 0);
        acc1 = __builtin_amdgcn_mfma_f32_16x16x32_bf16(af, b1, acc1, 0, 0, 0);
    }
    int col0 = tn0 * 16 + l15;
    int r0   = tm * 16 + hw * 4;
    float bv0 = bias[col0], bv1 = bias[col0 + 16];
#pragma unroll
    for (int j = 0; j < 4; ++j) {
        int row = base + r0 + j;
        if (row < NN) {
            out[(size_t)row * DIM + col0]      = acc0[j] + bv0;
            out[(size_t)row * DIM + col0 + 16] = acc1[j] + bv1;
        }
    }
}

// ---------------- SMALL path: round-1 per-edge ----------------
__global__ __launch_bounds__(256) void root_k(const float* __restrict__ x,
                                              const float* __restrict__ R,
                                              const float* __restrict__ b,
                                              float* __restrict__ out, int N) {
    int wid  = (blockIdx.x * 256 + threadIdx.x) >> 6;
    int lane = threadIdx.x & 63;
    if (wid >= N) return;
    wid = __builtin_amdgcn_readfirstlane(wid);
    const float* xs = x + (size_t)wid * DIM;
    float acc = b[lane];
#pragma unroll
    for (int k = 0; k < DIM; ++k)
        acc = fmaf(xs[k], R[k * DIM + lane], acc);
    out[(size_t)wid * DIM + lane] = acc;
}

__global__ __launch_bounds__(256) void edge_k(const float* __restrict__ x,
                                              const float* __restrict__ W,
                                              const int* __restrict__ srcv,
                                              const int* __restrict__ dstv,
                                              const int* __restrict__ etv,
                                              const int* __restrict__ cnt,
                                              float* __restrict__ out, int E) {
    int wid  = (blockIdx.x * 256 + threadIdx.x) >> 6;
    int lane = threadIdx.x & 63;
    if (wid >= E) return;
    int s = __builtin_amdgcn_readfirstlane(srcv[wid]);
    int d = __builtin_amdgcn_readfirstlane(dstv[wid]);
    int t = __builtin_amdgcn_readfirstlane(etv[wid]);
    const float* xs = x + (size_t)s * DIM;
    const float* w  = W + (size_t)t * DIM * DIM;
    float acc = 0.f;
#pragma unroll
    for (int k = 0; k < DIM; ++k)
        acc = fmaf(xs[k], w[k * DIM + lane], acc);
    float nrm = 1.0f / fmaxf((float)cnt[d * NREL + t], 1.0f);
    atomicAdd(&out[(size_t)d * DIM + lane], acc * nrm);
}

// ---------------- launch ----------------
extern "C" void kernel_launch(void* const* d_in, const int* in_sizes, int n_in,
                              void* d_out, int out_size, void* d_ws, size_t ws_size,
                              hipStream_t stream) {
    const float* x  = (const float*)d_in[0];   // [N, 64]
    const float* W  = (const float*)d_in[1];   // [2, 8, 64, 64]
    const float* R  = (const float*)d_in[2];   // [2, 64, 64]
    const float* B  = (const float*)d_in[3];   // [2, 64]
    const int*   ei = (const int*)d_in[4];     // [2, E]
    const int*   et = (const int*)d_in[5];     // [E]
    const int* src = ei;
    const int* dst = ei + NE;
    float* out = (float*)d_out;
    char* ws = (char*)d_ws;

    const size_t BIG_WS  = 144160000;
    const size_t FAST_WS = 41604096;

    if (ws_size >= BIG_WS) {
        // BIG v5 layout (Ag region now only hosts cnt/tmp aliases)
        bf16u* xb0  = (bf16u*)(ws + 0);              // (NN+1)*128 = 12,800,128
        bf16u* xb1  = (bf16u*)(ws + 12800256);       // 12,800,128
        int*   offp = (int*)  (ws + 25600512);       //  3,200,004
        float* inv  = (float*)(ws + 28800528);       //  3,200,000
        int*   esp  = (int*)  (ws + 32000544);       //  9,600,000 (padded edges)
        int*      cnt = (int*)     (ws + 41600544);  //  3,200,000
        unsigned* tmp = (unsigned*)(ws + 44800544);  //  6,400,000 (packed)
        bf16u* BtG  = (bf16u*)(ws + 144000544);      //    147,456
        int*   bsum = (int*)  (ws + 144148000);      //      3,128
        int*   bcnt = (int*)  (ws + 144151168);      //      1,568
        int*   bstart=(int*)  (ws + 144152768);      //      1,568 (NBUCK+1)
        int*   bcur = (int*)  (ws + 144154368);      //      1,568

        hipMemsetAsync(bcnt, 0, sizeof(int) * (NBUCK + 1), stream);
        bcount_k<<<(NE + 4095) / 4096, 256, 0, stream>>>(dst, et, bcnt);
        bscan_k<<<1, 512, 0, stream>>>(bcnt, bstart, bcur);
        part1_k<<<(NE + 2047) / 2048, 256, 0, stream>>>(src, dst, et, bcur, tmp);
        ncount_k<<<NBUCK, 256, 0, stream>>>(tmp, bstart, cnt);
        scanA_p<<<NBLK, 256, 0, stream>>>(cnt, bsum);
        scanB<<<1, 1024, 0, stream>>>(bsum);
        scanC_p<<<NBLK, 256, 0, stream>>>(cnt, bsum, offp, inv, esp);
        part2_k<<<NBUCK, 256, 0, stream>>>(tmp, bstart, offp, esp);
        btk<<<(2 * DIM * KTOT + 255) / 256, 256, 0, stream>>>(W, R, BtG);
        xcvt_k<<<((NN + 1) * DIM / 4 + 255) / 256, 256, 0, stream>>>(x, xb0, xb1);

        int gblk = (NN + 63) / 64;   // 1563
        fused_k<true ><<<gblk, 512, 0, stream>>>(xb0, offp, inv, esp, BtG, B, (void*)xb1);
        fused_k<false><<<gblk, 512, 0, stream>>>(xb1, offp, inv, esp, BtG + DIM * KTOT,
                                                 B + DIM, (void*)out);
    } else if (ws_size >= FAST_WS) {
        // round-4 layout (unpadded CSR)
        float* x1  = (float*)(ws + 0);
        int*   cnt = (int*)  (ws + 25600000);
        int*   off = (int*)  (ws + 28800000);
        int*   cur = (int*)  (ws + 32000016);
        int*   es  = (int*)  (ws + 35200016);
        int*   bsum= (int*)  (ws + 41600016);
        bf16u* BtG = (bf16u*)(ws + 32000016);        // alias over cur

        hipMemsetAsync(cnt, 0, sizeof(int) * NSEG, stream);
        count_k<<<(NE + 255) / 256, 256, 0, stream>>>(dst, et, cnt, NE);
        scanA<<<NBLK, 256, 0, stream>>>(cnt, bsum);
        scanB<<<1, 1024, 0, stream>>>(bsum);
        scanC<<<NBLK, 256, 0, stream>>>(cnt, bsum, off, cur);
        scatter_k<<<(NE + 255) / 256, 256, 0, stream>>>(src, dst, et, cur, es, NE);
        btk<<<(2 * DIM * KTOT + 255) / 256, 256, 0, stream>>>(W, R, BtG);

        int nblk = (NN + 63) / 64;
        layer_k<<<nblk, 512, 0, stream>>>(x,  BtG,              B,       off, es, x1);
        layer_k<<<nblk, 512, 0, stream>>>(x1, BtG + DIM * KTOT, B + DIM, off, es, out);
    } else {
        float* x1  = (float*)ws;
        int*   cnt = (int*)(ws + 25600000);
        hipMemsetAsync(cnt, 0, sizeof(int) * NSEG, stream);
        count_k<<<(NE + 255) / 256, 256, 0, stream>>>(dst, et, cnt, NE);
        root_k<<<(NN * 64) / 256 + 1, 256, 0, stream>>>(x, R, B, x1, NN);
        edge_k<<<(NE * 64) / 256, 256, 0, stream>>>(x, W, src, dst, et, cnt, x1, NE);
        root_k<<<(NN * 64) / 256 + 1, 256, 0, stream>>>(x1, R + DIM * DIM, B + DIM, out, NN);
        edge_k<<<(NE * 64) / 256, 256, 0, stream>>>(x1, W + NREL * DIM * DIM, src, dst, et, cnt, out, NE);
    }
}

// Round 14
// 374.165 us; speedup vs baseline: 1.2357x; 1.2357x over previous
//
#include <hip/hip_runtime.h>

#define NN    100000
#define NE    1600000
#define DIM   64
#define NREL  8
#define NSEG  (NN * NREL)                       // 800000 (dst,rel) segments
#define NTOT  (NSEG + 1)                        // off[] has a sentinel end
#define CHUNK 1024
#define NBLK  ((NTOT + CHUNK - 1) / CHUNK)      // 782
#define KTOT  (9 * DIM)                         // 576: 8 relations + root (B stack)
#define KAGG  (8 * DIM)                         // 512: Ag has no root slot
#define APAD  (KTOT + 8)                        // MID-path LDS row pad
#define APAD2 (KAGG + 8)                        // 520 bf16 rows in gemm2 LDS
#define ESPMAX (NE + NSEG)                      // padded edge list worst case
#define SEGB  2048                              // segments per bucket
#define NBUCK ((NSEG + SEGB - 1) / SEGB)        // 391 buckets
#define BUCKCAP 5120                            // fixed bucket region (16 sigma margin)

typedef unsigned short bf16u;
using short8  = __attribute__((ext_vector_type(8))) short;
using bfx4    = __attribute__((ext_vector_type(4))) unsigned short;
using f32x4   = __attribute__((ext_vector_type(4))) float;
using float4v = __attribute__((ext_vector_type(4))) float;

#if defined(__has_builtin)
#if __has_builtin(__builtin_amdgcn_make_buffer_rsrc) && \
    __has_builtin(__builtin_amdgcn_raw_buffer_load_b32) && \
    __has_builtin(__builtin_amdgcn_raw_buffer_store_b32)
#define HAVE_BUF 1
#endif
#endif

#ifdef HAVE_BUF
__device__ __forceinline__ __amdgpu_buffer_rsrc_t mk_rsrc(const void* p, unsigned bytes) {
    return __builtin_amdgcn_make_buffer_rsrc(const_cast<void*>(p), (short)0,
                                             (int)bytes, 0x00020000);
}
#endif

__device__ __forceinline__ bf16u f2bf(float v) {   // f32 -> bf16 RNE
    unsigned b = __float_as_uint(v);
    return (bf16u)((b + 0x7FFFu + ((b >> 16) & 1u)) >> 16);
}
__device__ __forceinline__ float bf2f(bf16u u) {
    return __uint_as_float((unsigned)u << 16);
}

// exclusive prefix over blockDim.x values
__device__ __forceinline__ int block_exscan(int v, int* lds) {
    int tid = threadIdx.x;
    lds[tid] = v;
    __syncthreads();
    for (int s = 1; s < (int)blockDim.x; s <<= 1) {
        int t = (tid >= s) ? lds[tid - s] : 0;
        __syncthreads();
        lds[tid] += t;
        __syncthreads();
    }
    return lds[tid] - v;
}

// ---------------- bucketed CSR build (BIG path, fixed-capacity buckets) ----------------
__global__ __launch_bounds__(256) void binit_k(int* __restrict__ bcur) {
    int i = blockIdx.x * 256 + threadIdx.x;
    if (i < NBUCK) bcur[i] = i * BUCKCAP;
}

// block-local binning append: packed (src<<11 | c&2047) into per-bucket fixed regions
__global__ __launch_bounds__(256) void part1_k(const int* __restrict__ src,
                                               const int* __restrict__ dst,
                                               const int* __restrict__ et,
                                               int* __restrict__ bcur,
                                               unsigned* __restrict__ tmp) {
    __shared__ int cntl[NBUCK];
    __shared__ int basel[NBUCK];
    for (int i = threadIdx.x; i < NBUCK; i += 256) cntl[i] = 0;
    __syncthreads();
    const int base = blockIdx.x * 2048;
    int cs[8], rs[8]; unsigned pw[8];
#pragma unroll
    for (int j = 0; j < 8; ++j) {
        int i = base + j * 256 + threadIdx.x;
        cs[j] = -1;
        if (i < NE) {
            cs[j] = dst[i] * NREL + et[i];
            pw[j] = ((unsigned)src[i] << 11) | ((unsigned)cs[j] & 2047u);
            rs[j] = atomicAdd(&cntl[cs[j] >> 11], 1);
        }
    }
    __syncthreads();
    for (int i = threadIdx.x; i < NBUCK; i += 256)
        basel[i] = cntl[i] ? atomicAdd(&bcur[i], cntl[i]) : 0;
    __syncthreads();
#pragma unroll
    for (int j = 0; j < 8; ++j)
        if (cs[j] >= 0)
            tmp[basel[cs[j] >> 11] + rs[j]] = pw[j];
}

// per-bucket dense segment counts (from packed tmp)
__global__ __launch_bounds__(256) void ncount_k(const unsigned* __restrict__ tmp,
                                                const int* __restrict__ bcur,
                                                int* __restrict__ cnt) {
    __shared__ int rk[SEGB];
    const int b = blockIdx.x, c0 = b * SEGB;
    const int nsb = min(SEGB, NSEG - c0);
    for (int i = threadIdx.x; i < SEGB; i += 256) rk[i] = 0;
    __syncthreads();
    const int e0 = b * BUCKCAP, e1 = bcur[b];
    for (int e = e0 + threadIdx.x; e < e1; e += 256)
        atomicAdd(&rk[tmp[e] & 2047u], 1);
    __syncthreads();
    for (int i = threadIdx.x; i < nsb; i += 256) cnt[c0 + i] = rk[i];
}

// per-bucket scatter into L2-resident esp window
__global__ __launch_bounds__(256) void part2_k(const unsigned* __restrict__ tmp,
                                               const int* __restrict__ bcur,
                                               const int* __restrict__ offp,
                                               int* __restrict__ esp) {
    __shared__ int rk[SEGB];
    const int b = blockIdx.x, c0 = b * SEGB;
    for (int i = threadIdx.x; i < SEGB; i += 256) rk[i] = 0;
    __syncthreads();
    const int e0 = b * BUCKCAP, e1 = bcur[b];
    for (int e = e0 + threadIdx.x; e < e1; e += 256) {
        unsigned w = tmp[e];
        int lc = (int)(w & 2047u);
        int r = atomicAdd(&rk[lc], 1);
        esp[offp[c0 + lc] + r] = (int)(w >> 11);
    }
}

// ---------------- legacy CSR build (MID/SMALL fallbacks) ----------------
__global__ __launch_bounds__(256) void count_k(const int* __restrict__ dst,
                                               const int* __restrict__ et,
                                               int* __restrict__ cnt, int E) {
    int i = blockIdx.x * 256 + threadIdx.x;
    if (i < E) atomicAdd(&cnt[dst[i] * NREL + et[i]], 1);
}

__global__ __launch_bounds__(256) void scanA_p(const int* __restrict__ cnt,
                                               int* __restrict__ bsum) {
    __shared__ int lds[256];
    int base = blockIdx.x * CHUNK + threadIdx.x * 4;
    int s = 0;
#pragma unroll
    for (int j = 0; j < 4; ++j) {
        int i = base + j;
        if (i < NSEG) { int v = cnt[i]; s += v + (v & 1); }
    }
    int e = block_exscan(s, lds);
    if (threadIdx.x == 255) bsum[blockIdx.x] = e + s;
}

__global__ __launch_bounds__(1024) void scanB(int* __restrict__ bsum) {
    __shared__ int lds[1024];
    int v = (threadIdx.x < NBLK) ? bsum[threadIdx.x] : 0;
    int e = block_exscan(v, lds);
    if (threadIdx.x < NBLK) bsum[threadIdx.x] = e;
}

__global__ __launch_bounds__(256) void scanC_p(const int* __restrict__ cnt,
                                               const int* __restrict__ bsum,
                                               int* __restrict__ offp,
                                               float* __restrict__ inv,
                                               int* __restrict__ esp) {
    __shared__ int lds[256];
    int base = blockIdx.x * CHUNK + threadIdx.x * 4;
    int c4[4], v4[4]; int s = 0;
#pragma unroll
    for (int j = 0; j < 4; ++j) {
        int i = base + j;
        c4[j] = (i < NSEG) ? cnt[i] : 0;
        v4[j] = c4[j] + (c4[j] & 1);
        s += v4[j];
    }
    int e = block_exscan(s, lds) + bsum[blockIdx.x];
#pragma unroll
    for (int j = 0; j < 4; ++j) {
        int i = base + j;
        if (i < NSEG) {
            offp[i] = e;
            inv[i]  = (c4[j] > 0) ? 1.0f / (float)c4[j] : 0.0f;
            if (c4[j] & 1) esp[e + c4[j]] = NN;       // dummy -> zero row
            e += v4[j];
        } else if (i == NSEG) { offp[i] = e; }
    }
}

__global__ __launch_bounds__(256) void scanA(const int* __restrict__ cnt,
                                             int* __restrict__ bsum) {
    __shared__ int lds[256];
    int base = blockIdx.x * CHUNK + threadIdx.x * 4;
    int s = 0;
#pragma unroll
    for (int j = 0; j < 4; ++j) { int i = base + j; if (i < NSEG) s += cnt[i]; }
    int e = block_exscan(s, lds);
    if (threadIdx.x == 255) bsum[blockIdx.x] = e + s;
}

__global__ __launch_bounds__(256) void scanC(const int* __restrict__ cnt,
                                             const int* __restrict__ bsum,
                                             int* __restrict__ off,
                                             int* __restrict__ cur) {
    __shared__ int lds[256];
    int base = blockIdx.x * CHUNK + threadIdx.x * 4;
    int v[4]; int s = 0;
#pragma unroll
    for (int j = 0; j < 4; ++j) { int i = base + j; v[j] = (i < NSEG) ? cnt[i] : 0; s += v[j]; }
    int e = block_exscan(s, lds) + bsum[blockIdx.x];
#pragma unroll
    for (int j = 0; j < 4; ++j) {
        int i = base + j;
        if (i < NSEG)       { off[i] = e; cur[i] = e; e += v[j]; }
        else if (i == NSEG) { off[i] = e; }
    }
}

__global__ __launch_bounds__(256) void scatter_k(const int* __restrict__ src,
                                                 const int* __restrict__ dst,
                                                 const int* __restrict__ et,
                                                 int* __restrict__ cur,
                                                 int* __restrict__ es, int E) {
    int i = blockIdx.x * 256 + threadIdx.x;
    if (i < E) {
        int c = dst[i] * NREL + et[i];
        int p = atomicAdd(&cur[c], 1);
        es[p] = src[i];
    }
}

// ---------------- f32 -> bf16 convert (x -> xb0) + zero rows of xb0 AND xb1 ----------------
__global__ __launch_bounds__(256) void xcvt_k(const float* __restrict__ x,
                                              bf16u* __restrict__ xb,
                                              bf16u* __restrict__ xb1) {
    int i = blockIdx.x * 256 + threadIdx.x;          // 4 elems per thread
    int e4 = i * 4;
    if (e4 < NN * DIM) {
        float4v v = *(const float4v*)(x + e4);
        bfx4 o;
        o.x = f2bf(v.x); o.y = f2bf(v.y); o.z = f2bf(v.z); o.w = f2bf(v.w);
        *(bfx4*)(xb + e4) = o;
    } else if (e4 < (NN + 1) * DIM) {
        bfx4 z = {0, 0, 0, 0};
        *(bfx4*)(xb + e4)  = z;                      // zero row for dummy edges
        *(bfx4*)(xb1 + e4) = z;                      // layer-1 intermediate zero row
    }
}

// ---------------- B-stack transpose: Bt[l][n][k] = Bs[l][k][n] in bf16 ----------------
__global__ __launch_bounds__(256) void btk(const float* __restrict__ W,
                                           const float* __restrict__ R,
                                           bf16u* __restrict__ BtG) {
    int idx = blockIdx.x * 256 + threadIdx.x;     // [2][64][576]
    if (idx >= 2 * DIM * KTOT) return;
    int k = idx % KTOT;
    int n = (idx / KTOT) & (DIM - 1);
    int l = idx / (KTOT * DIM);
    float v;
    if (k < 8 * DIM) v = W[(((size_t)l * NREL + (k >> 6)) * DIM + (k & 63)) * DIM + n];
    else             v = R[((size_t)l * DIM + (k - 8 * DIM)) * DIM + n];
    BtG[idx] = f2bf(v);
}

// ---------------- BIG path: pair-gather aggregation, 16-deep + ids prefetch ----------------
__global__ __launch_bounds__(256, 8) void agg2_k(
    const bf16u* __restrict__ xb, const int* __restrict__ offp,
    const float* __restrict__ invf, const int* __restrict__ esp,
    bf16u* __restrict__ Ag)
{
    const int lane = threadIdx.x & 63;
    const int wv   = threadIdx.x >> 6;
    const int d0   = (blockIdx.x * 4 + wv) * 8;          // NN % 8 == 0, no tail
    if (d0 >= NN) return;
    const int c0 = d0 * NREL;

#ifdef HAVE_BUF
    const __amdgpu_buffer_rsrc_t xrsrc = mk_rsrc(xb,  (unsigned)((NN + 1) * DIM * 2));
    const __amdgpu_buffer_rsrc_t ersrc = mk_rsrc(esp, (unsigned)(ESPMAX * 4));
    const __amdgpu_buffer_rsrc_t arsrc = mk_rsrc(Ag,  0xFFFFFFFFu);
    const int xoff4 = (lane & 31) * 4;
#define ESLD(pos)  (int)__builtin_amdgcn_raw_buffer_load_b32(ersrc, (pos) * 4, 0, 0)
#define XLD(sv)    __builtin_amdgcn_raw_buffer_load_b32(xrsrc, ((sv) << 7) + xoff4, 0, 0)
#define AGST(pk, seg)                                                          \
    if (lane < 32)                                                             \
        __builtin_amdgcn_raw_buffer_store_b32((pk), arsrc, (lane & 31) * 4,    \
            ((d0 + ((seg) >> 3)) * KAGG + ((seg) & 7) * DIM) * 2, 0);
#else
#define ESLD(pos)  esp[min((pos), ESPMAX - 1)]
#define XLD(sv)    (*(const unsigned*)(xb + (size_t)(sv) * DIM + (lane & 31) * 2))
#define AGST(pk, seg)                                                          \
    if (lane < 32)                                                             \
        *(unsigned*)(Ag + ((size_t)(d0 + ((seg) >> 3)) * KAGG                  \
                           + ((seg) & 7) * DIM + (lane & 31) * 2)) = (pk);
#endif

    int offv = offp[c0 + 1 + lane];                      // bounds 1..64 (seg ends)
    int invv = ((const int*)invf)[c0 + lane];            // 1/real_cnt per segment
    int pBase = __builtin_amdgcn_readfirstlane(offp[c0]); // even
    int pEnd  = __builtin_amdgcn_readlane(offv, 63);

    int idsbase = pBase;
    int ids     = ESLD(idsbase + lane);                  // current 64-edge window
    int ids_nxt = ESLD(idsbase + 64 + lane);             // prefetched next window

    unsigned q0 = 0, q1 = 0, q2 = 0, q3 = 0, q4 = 0, q5 = 0, q6 = 0, q7 = 0,
             q8 = 0, q9 = 0, qa = 0, qb = 0, qc = 0, qd = 0, qe = 0, qf = 0;
    {   // prime 16 pair-slots (idx <= 31, no reload needed)
        int pf = pBase;
#define PRIME(Q) if (pf < pEnd) {                                             \
        int idx = pf - idsbase;                                               \
        int sv0 = __builtin_amdgcn_readlane(ids, idx);                        \
        int sv1 = __builtin_amdgcn_readlane(ids, idx + 1);                    \
        int sv  = (lane < 32) ? sv0 : sv1;                                    \
        Q = XLD(sv); }                                                        \
        pf += 2;
        PRIME(q0) PRIME(q1) PRIME(q2) PRIME(q3)
        PRIME(q4) PRIME(q5) PRIME(q6) PRIME(q7)
        PRIME(q8) PRIME(q9) PRIME(qa) PRIME(qb)
        PRIME(qc) PRIME(qd) PRIME(qe) PRIME(qf)
#undef PRIME
    }
    int seg = 0, p = pBase;
    int se      = __builtin_amdgcn_readlane(offv, 0);
    float invn  = __int_as_float(__builtin_amdgcn_readlane(invv, 0));
    float accA = 0.f, accB = 0.f;

    // window crossings land exactly at idx==64 (p even-stepped from even base),
    // so the prefetched ids_nxt aligns with the new window.
#define STEP(Q) {                                                             \
        while (p == se) {   /* flush segment (handles empty segs) */          \
            float ta = accA + __shfl_xor(accA, 32);                           \
            float tb = accB + __shfl_xor(accB, 32);                           \
            unsigned pk = (unsigned)f2bf(ta * invn)                           \
                        | ((unsigned)f2bf(tb * invn) << 16);                  \
            AGST(pk, seg)                                                     \
            accA = 0.f; accB = 0.f;                                           \
            if (++seg >= 64) goto agg_done;                                   \
            se   = __builtin_amdgcn_readlane(offv, seg);                      \
            invn = __int_as_float(__builtin_amdgcn_readlane(invv, seg));      \
        }                                                                     \
        accA += __uint_as_float(Q << 16);                                     \
        accB += __uint_as_float(Q & 0xffff0000u);                             \
        int pn = p + 32;                                                      \
        if (pn < pEnd) {                                                      \
            int idx = pn - idsbase;                                           \
            if (idx >= 64) { idsbase = pn;                                    \
                ids = ids_nxt;                                                \
                ids_nxt = ESLD(idsbase + 64 + lane); idx = 0; }               \
            int sv0 = __builtin_amdgcn_readlane(ids, idx);                    \
            int sv1 = __builtin_amdgcn_readlane(ids, idx + 1);                \
            int sv  = (lane < 32) ? sv0 : sv1;                                \
            Q = XLD(sv);                                                      \
        }                                                                     \
        p += 2; }

    for (;;) { STEP(q0) STEP(q1) STEP(q2) STEP(q3)
               STEP(q4) STEP(q5) STEP(q6) STEP(q7)
               STEP(q8) STEP(q9) STEP(qa) STEP(qb)
               STEP(qc) STEP(qd) STEP(qe) STEP(qf) }
agg_done: ;
#undef STEP
#undef ESLD
#undef XLD
#undef AGST
}

// ---------------- BIG path: GEMM  C[64x64] = [A(512) | xroot(64)] @ Bstack ----------------
template<bool BF16OUT>
__global__ __launch_bounds__(512, 4) void gemm2_k(
    const bf16u* __restrict__ Ag, const bf16u* __restrict__ xb,
    const bf16u* __restrict__ BtG, const float* __restrict__ bias,
    void* __restrict__ outv)
{
    __shared__ bf16u A[64 * APAD2];
    const int tid  = threadIdx.x;
    const int base = blockIdx.x * 64;

    // stage 64 rows x 512 of Ag -> padded LDS
    {
        const int srow = tid >> 3, scg = tid & 7;
        const bf16u* gsrc = Ag + (size_t)min(base + srow, NN - 1) * KAGG + scg * 8;
        bf16u* ldst = &A[srow * APAD2 + scg * 8];
#pragma unroll
        for (int j = 0; j < 8; ++j)
            *(short8*)(ldst + j * 64) = *(const short8*)(gsrc + j * 64);
    }
    __syncthreads();

    const int lane = tid & 63, wv = tid >> 6;
    const int l15 = lane & 15, hw = lane >> 4;
    const int tid0 = wv * 2;                 // two N-adjacent 16x16 tiles per wave
    const int tm = tid0 >> 2, tn0 = tid0 & 3;
    const bf16u* Arow = &A[(tm * 16 + l15) * APAD2 + hw * 8];
    const bf16u* xrow = xb + (size_t)min(base + tm * 16 + l15, NN - 1) * DIM + hw * 8;
    const bf16u* B0   = &BtG[(size_t)(tn0 * 16 + l15) * KTOT + hw * 8];
    const bf16u* B1   = B0 + 16 * KTOT;
    f32x4 acc0 = {0.f, 0.f, 0.f, 0.f}, acc1 = {0.f, 0.f, 0.f, 0.f};
#pragma unroll
    for (int ks = 0; ks < KTOT / 32; ++ks) {         // 16 LDS steps + 2 root steps
        short8 af = (ks < 16) ? *(const short8*)(Arow + ks * 32)
                              : *(const short8*)(xrow + (ks - 16) * 32);
        short8 b0 = *(const short8*)(B0 + ks * 32);
        short8 b1 = *(const short8*)(B1 + ks * 32);
        acc0 = __builtin_amdgcn_mfma_f32_16x16x32_bf16(af, b0, acc0, 0, 0, 0);
        acc1 = __builtin_amdgcn_mfma_f32_16x16x32_bf16(af, b1, acc1, 0, 0, 0);
    }
    // C/D: col = lane&15, row = (lane>>4)*4 + reg   [m89-verified]
    int col0 = tn0 * 16 + l15;
    int r0   = tm * 16 + hw * 4;
    float bv0 = bias[col0], bv1 = bias[col0 + 16];
#pragma unroll
    for (int j = 0; j < 4; ++j) {
        int row = base + r0 + j;
        if (row < NN) {
            if constexpr (BF16OUT) {
                bf16u* out = (bf16u*)outv;
                out[(size_t)row * DIM + col0]      = f2bf(acc0[j] + bv0);
                out[(size_t)row * DIM + col0 + 16] = f2bf(acc1[j] + bv1);
            } else {
                float* out = (float*)outv;
                out[(size_t)row * DIM + col0]      = acc0[j] + bv0;
                out[(size_t)row * DIM + col0 + 16] = acc1[j] + bv1;
            }
        }
    }
}

// ---------------- MID path: round-4 fused kernel (f32 gather, unpadded CSR) ----------------
__global__ __launch_bounds__(512, 4) void layer_k(
    const float* __restrict__ xin, const bf16u* __restrict__ BtG,
    const float* __restrict__ bias, const int* __restrict__ off,
    const int* __restrict__ es, float* __restrict__ out)
{
    __shared__ bf16u A[64 * APAD];
    const int lane = threadIdx.x & 63;
    const int wv   = threadIdx.x >> 6;
    const int base = blockIdx.x * 64;
    const int d0   = base + wv * 8;
    const int nds  = min(8, NN - d0);
    bf16u* Aw = &A[wv * 8 * APAD];

    if (nds > 0) {
        const int c0   = d0 * NREL;
        const int nseg = nds * NREL;
        int s1v = off[min(c0 + lane + 1, NSEG)];
        int pBase = off[min(c0, NSEG)];
        pBase = __builtin_amdgcn_readfirstlane(pBase);
        int pEnd  = __builtin_amdgcn_readlane(s1v, nseg - 1);

        float xroot[8];
#pragma unroll
        for (int i = 0; i < 8; ++i)
            xroot[i] = xin[(size_t)min(d0 + i, NN - 1) * DIM + lane];

        int idsbase = pBase;
        int ids = es[min(idsbase + lane, NE - 1)];

        float q0 = 0.f, q1 = 0.f, q2 = 0.f, q3 = 0.f,
              q4 = 0.f, q5 = 0.f, q6 = 0.f, q7 = 0.f;
        {
            int pf = pBase;
#define PRIME(Q) if (pf < pEnd) { int idx = pf - idsbase;                     \
        int sv = __builtin_amdgcn_readlane(ids, idx);                         \
        Q = xin[(size_t)sv * DIM + lane]; } ++pf;
            PRIME(q0) PRIME(q1) PRIME(q2) PRIME(q3)
            PRIME(q4) PRIME(q5) PRIME(q6) PRIME(q7)
#undef PRIME
        }
        int seg = 0, segStart = pBase, p = pBase;
        int se = __builtin_amdgcn_readlane(s1v, 0);
        float acc = 0.f;

#define STEP(Q) {                                                             \
        while (p == se) {                                                     \
            int n = se - segStart;                                            \
            float invn = (n > 0) ? 1.0f / (float)n : 0.f;                     \
            Aw[(seg >> 3) * APAD + (seg & 7) * DIM + lane] = f2bf(acc * invn);\
            acc = 0.f; segStart = p;                                          \
            if (++seg >= nseg) goto agg_done;                                 \
            se = __builtin_amdgcn_readlane(s1v, seg);                         \
        }                                                                     \
        acc += Q;                                                             \
        int pn = p + 8;                                                       \
        if (pn < pEnd) {                                                      \
            int idx = pn - idsbase;                                           \
            if (idx >= 64) { idsbase = pn;                                    \
                ids = es[min(idsbase + lane, NE - 1)]; idx = 0; }             \
            int sv = __builtin_amdgcn_readlane(ids, idx);                     \
            Q = xin[(size_t)sv * DIM + lane];                                 \
        }                                                                     \
        ++p; }

        for (;;) { STEP(q0) STEP(q1) STEP(q2) STEP(q3)
                   STEP(q4) STEP(q5) STEP(q6) STEP(q7) }
agg_done: ;
#undef STEP

#pragma unroll
        for (int i = 0; i < 8; ++i) {
            if (i < nds) Aw[i * APAD + 8 * DIM + lane] = f2bf(xroot[i]);
            else {
#pragma unroll
                for (int r = 0; r < 9; ++r) Aw[i * APAD + r * DIM + lane] = 0;
            }
        }
    } else {
#pragma unroll
        for (int i = 0; i < 8; ++i)
#pragma unroll
            for (int r = 0; r < 9; ++r) Aw[i * APAD + r * DIM + lane] = 0;
    }
    __syncthreads();

    const int l15 = lane & 15, hw = lane >> 4;
    const int tid0 = wv * 2;
    const int tm = tid0 >> 2, tn0 = tid0 & 3;
    const bf16u* Arow = &A[(tm * 16 + l15) * APAD + hw * 8];
    const bf16u* B0   = &BtG[(size_t)(tn0 * 16 + l15) * KTOT + hw * 8];
    const bf16u* B1   = B0 + 16 * KTOT;
    f32x4 acc0 = {0.f, 0.f, 0.f, 0.f}, acc1 = {0.f, 0.f, 0.f, 0.f};
#pragma unroll
    for (int ks = 0; ks < KTOT / 32; ++ks) {
        short8 af = *(const short8*)(Arow + ks * 32);
        short8 b0 = *(const short8*)(B0 + ks * 32);
        short8 b1 = *(const short8*)(B1 + ks * 32);
        acc0 = __builtin_amdgcn_mfma_f32_16x16x32_bf16(af, b0, acc0, 0, 0, 0);
        acc1 = __builtin_amdgcn_mfma_f32_16x16x32_bf16(af, b1, acc1, 0, 0, 0);
    }
    int col0 = tn0 * 16 + l15;
    int r0   = tm * 16 + hw * 4;
    float bv0 = bias[col0], bv1 = bias[col0 + 16];
#pragma unroll
    for (int j = 0; j < 4; ++j) {
        int row = base + r0 + j;
        if (row < NN) {
            out[(size_t)row * DIM + col0]      = acc0[j] + bv0;
            out[(size_t)row * DIM + col0 + 16] = acc1[j] + bv1;
        }
    }
}

// ---------------- SMALL path: round-1 per-edge ----------------
__global__ __launch_bounds__(256) void root_k(const float* __restrict__ x,
                                              const float* __restrict__ R,
                                              const float* __restrict__ b,
                                              float* __restrict__ out, int N) {
    int wid  = (blockIdx.x * 256 + threadIdx.x) >> 6;
    int lane = threadIdx.x & 63;
    if (wid >= N) return;
    wid = __builtin_amdgcn_readfirstlane(wid);
    const float* xs = x + (size_t)wid * DIM;
    float acc = b[lane];
#pragma unroll
    for (int k = 0; k < DIM; ++k)
        acc = fmaf(xs[k], R[k * DIM + lane], acc);
    out[(size_t)wid * DIM + lane] = acc;
}

__global__ __launch_bounds__(256) void edge_k(const float* __restrict__ x,
                                              const float* __restrict__ W,
                                              const int* __restrict__ srcv,
                                              const int* __restrict__ dstv,
                                              const int* __restrict__ etv,
                                              const int* __restrict__ cnt,
                                              float* __restrict__ out, int E) {
    int wid  = (blockIdx.x * 256 + threadIdx.x) >> 6;
    int lane = threadIdx.x & 63;
    if (wid >= E) return;
    int s = __builtin_amdgcn_readfirstlane(srcv[wid]);
    int d = __builtin_amdgcn_readfirstlane(dstv[wid]);
    int t = __builtin_amdgcn_readfirstlane(etv[wid]);
    const float* xs = x + (size_t)s * DIM;
    const float* w  = W + (size_t)t * DIM * DIM;
    float acc = 0.f;
#pragma unroll
    for (int k = 0; k < DIM; ++k)
        acc = fmaf(xs[k], w[k * DIM + lane], acc);
    float nrm = 1.0f / fmaxf((float)cnt[d * NREL + t], 1.0f);
    atomicAdd(&out[(size_t)d * DIM + lane], acc * nrm);
}

// ---------------- launch ----------------
extern "C" void kernel_launch(void* const* d_in, const int* in_sizes, int n_in,
                              void* d_out, int out_size, void* d_ws, size_t ws_size,
                              hipStream_t stream) {
    const float* x  = (const float*)d_in[0];   // [N, 64]
    const float* W  = (const float*)d_in[1];   // [2, 8, 64, 64]
    const float* R  = (const float*)d_in[2];   // [2, 64, 64]
    const float* B  = (const float*)d_in[3];   // [2, 64]
    const int*   ei = (const int*)d_in[4];     // [2, E]
    const int*   et = (const int*)d_in[5];     // [E]
    const int* src = ei;
    const int* dst = ei + NE;
    float* out = (float*)d_out;
    char* ws = (char*)d_ws;

    const size_t BIG_WS  = 144160000;
    const size_t FAST_WS = 41604096;

    if (ws_size >= BIG_WS) {
        // BIG v6 layout (tmp = fixed-capacity bucket regions, aliased in Ag)
        bf16u* xb0  = (bf16u*)(ws + 0);              // (NN+1)*128 = 12,800,128
        bf16u* xb1  = (bf16u*)(ws + 12800256);       // 12,800,128
        int*   offp = (int*)  (ws + 25600512);       //  3,200,004
        float* inv  = (float*)(ws + 28800528);       //  3,200,000
        int*   esp  = (int*)  (ws + 32000544);       //  9,600,000 (padded edges)
        bf16u* Ag   = (bf16u*)(ws + 41600544);       // 102,400,000 (K=512)
        int*      cnt = (int*)     (ws + 41600544);  // alias in Ag (dead before agg)
        unsigned* tmp = (unsigned*)(ws + 44800544);  // alias in Ag: 391*5120*4 = 8,007,680
        bf16u* BtG  = (bf16u*)(ws + 144000544);      //    147,456
        int*   bsum = (int*)  (ws + 144148000);      //      3,128
        int*   bcur = (int*)  (ws + 144154368);      //      1,568

        binit_k<<<(NBUCK + 255) / 256, 256, 0, stream>>>(bcur);
        part1_k<<<(NE + 2047) / 2048, 256, 0, stream>>>(src, dst, et, bcur, tmp);
        ncount_k<<<NBUCK, 256, 0, stream>>>(tmp, bcur, cnt);
        scanA_p<<<NBLK, 256, 0, stream>>>(cnt, bsum);
        scanB<<<1, 1024, 0, stream>>>(bsum);
        scanC_p<<<NBLK, 256, 0, stream>>>(cnt, bsum, offp, inv, esp);
        part2_k<<<NBUCK, 256, 0, stream>>>(tmp, bcur, offp, esp);
        btk<<<(2 * DIM * KTOT + 255) / 256, 256, 0, stream>>>(W, R, BtG);
        xcvt_k<<<((NN + 1) * DIM / 4 + 255) / 256, 256, 0, stream>>>(x, xb0, xb1);

        int gblk = (NN + 63) / 64;   // 1563
        int ablk = NN / 32;          // 3125 blocks x 4 waves x 8 dsts
        agg2_k<<<ablk, 256, 0, stream>>>(xb0, offp, inv, esp, Ag);
        gemm2_k<true ><<<gblk, 512, 0, stream>>>(Ag, xb0, BtG, B, (void*)xb1);
        agg2_k<<<ablk, 256, 0, stream>>>(xb1, offp, inv, esp, Ag);
        gemm2_k<false><<<gblk, 512, 0, stream>>>(Ag, xb1, BtG + DIM * KTOT, B + DIM, (void*)out);
    } else if (ws_size >= FAST_WS) {
        // round-4 layout (unpadded CSR)
        float* x1  = (float*)(ws + 0);
        int*   cnt = (int*)  (ws + 25600000);
        int*   off = (int*)  (ws + 28800000);
        int*   cur = (int*)  (ws + 32000016);
        int*   es  = (int*)  (ws + 35200016);
        int*   bsum= (int*)  (ws + 41600016);
        bf16u* BtG = (bf16u*)(ws + 32000016);        // alias over cur

        hipMemsetAsync(cnt, 0, sizeof(int) * NSEG, stream);
        count_k<<<(NE + 255) / 256, 256, 0, stream>>>(dst, et, cnt, NE);
        scanA<<<NBLK, 256, 0, stream>>>(cnt, bsum);
        scanB<<<1, 1024, 0, stream>>>(bsum);
        scanC<<<NBLK, 256, 0, stream>>>(cnt, bsum, off, cur);
        scatter_k<<<(NE + 255) / 256, 256, 0, stream>>>(src, dst, et, cur, es, NE);
        btk<<<(2 * DIM * KTOT + 255) / 256, 256, 0, stream>>>(W, R, BtG);

        int nblk = (NN + 63) / 64;
        layer_k<<<nblk, 512, 0, stream>>>(x,  BtG,              B,       off, es, x1);
        layer_k<<<nblk, 512, 0, stream>>>(x1, BtG + DIM * KTOT, B + DIM, off, es, out);
    } else {
        float* x1  = (float*)ws;
        int*   cnt = (int*)(ws + 25600000);
        hipMemsetAsync(cnt, 0, sizeof(int) * NSEG, stream);
        count_k<<<(NE + 255) / 256, 256, 0, stream>>>(dst, et, cnt, NE);
        root_k<<<(NN * 64) / 256 + 1, 256, 0, stream>>>(x, R, B, x1, NN);
        edge_k<<<(NE * 64) / 256, 256, 0, stream>>>(x, W, src, dst, et, cnt, x1, NE);
        root_k<<<(NN * 64) / 256 + 1, 256, 0, stream>>>(x1, R + DIM * DIM, B + DIM, out, NN);
        edge_k<<<(NE * 64) / 256, 256, 0, stream>>>(x1, W + NREL * DIM * DIM, src, dst, et, cnt, out, NE);
    }
}